// Round 9
// baseline (97.343 us; speedup 1.0000x reference)
//
#include <hip/hip_runtime.h>
#include <float.h>
#include <math.h>

#define T_DIM 2048
#define C_DIM 512
#define QKV_LD 1536
#define NBLK 512

typedef float f32x4 __attribute__((ext_vector_type(4)));
typedef short s16x8 __attribute__((ext_vector_type(8)));

__device__ __forceinline__ unsigned short f2bf(float f) {
  unsigned u = __float_as_uint(f);
  return (unsigned short)((u + 0x7fffu + ((u >> 16) & 1u)) >> 16);
}

// async 16B global->LDS; LDS dest must be wave-uniform base + lane*16.
__device__ __forceinline__ void load16_to_lds(const void* g, void* l) {
  __builtin_amdgcn_global_load_lds(
      (const __attribute__((address_space(1))) unsigned int*)g,
      (__attribute__((address_space(3))) unsigned int*)(unsigned int)(unsigned long long)l,
      16, 0, 0);
}

// ---------------------------------------------------------------------------
// prep: cast x -> bf16; transpose+cast Wqkv, Wout.  512 blocks. (unchanged)
// ---------------------------------------------------------------------------
__global__ __launch_bounds__(256) void prep_kernel(const float* __restrict__ x,
                                                   const float* __restrict__ Wqkv,
                                                   const float* __restrict__ Wout,
                                                   unsigned short* __restrict__ xbf,
                                                   unsigned short* __restrict__ WqkvT,
                                                   unsigned short* __restrict__ WoutT) {
  __shared__ float tile[32][33];
  const int tid = threadIdx.x, bid = blockIdx.x;

  const float4* xs4 = (const float4*)x;
  for (int i = bid * 256 + tid; i < (T_DIM * C_DIM) / 4; i += NBLK * 256) {
    float4 v = xs4[i];
    ushort4 o;
    o.x = f2bf(v.x); o.y = f2bf(v.y); o.z = f2bf(v.z); o.w = f2bf(v.w);
    ((ushort4*)xbf)[i] = o;
  }
  const int tx = tid & 31, ty = tid >> 5;
  for (int tt = bid; tt < 1024; tt += NBLK) {
    const float* src; unsigned short* dst; int Cc, R, bx, by;
    if (tt < 768) { src = Wqkv; dst = WqkvT; Cc = QKV_LD; R = C_DIM; bx = (tt % 48) * 32; by = (tt / 48) * 32; }
    else { int u = tt - 768; src = Wout; dst = WoutT; Cc = C_DIM; R = C_DIM; bx = (u & 15) * 32; by = (u >> 4) * 32; }
    __syncthreads();
#pragma unroll
    for (int i = 0; i < 4; ++i) { int r = ty + i * 8; tile[r][tx] = src[(size_t)(by + r) * Cc + bx + tx]; }
    __syncthreads();
#pragma unroll
    for (int i = 0; i < 4; ++i) { int r = ty + i * 8; dst[(size_t)(bx + r) * R + by + tx] = f2bf(tile[tx][r]); }
  }
}

// ---------------------------------------------------------------------------
// bf16 MFMA GEMM: C = A[M,K] * BT[N,K]^T.  One tile per block, BK=64.
// gemm1 uses BN=96 -> grid 16x16 = 256 blocks, exactly 1/CU (no tail).
// ---------------------------------------------------------------------------
template <int BM, int BN, bool OUT16>
__device__ __forceinline__ void gemm_body(const unsigned short* __restrict__ A,
                                          const unsigned short* __restrict__ BT,
                                          void* __restrict__ Cp,
                                          int N, int K, int tilesX,
                                          unsigned short* lA, unsigned short* lB,
                                          int tid, int bid) {
  constexpr int BK = 64;
  constexpr int BM2 = BM / 2, BN2 = BN / 2;
  constexpr int MT = BM2 / 16, NT = BN2 / 16;
  constexpr int IA = BM / 32;   // 16B chunks: BM*8 per tile / 256 threads
  constexpr int IB = BN / 32;
  const int lane = tid & 63, w = tid >> 6, wr = w >> 1, wc = w & 1;
  const int fm = lane & 15, q8 = (lane >> 4) * 8, q4 = lane >> 4;

  const int m0 = (bid / tilesX) * BM, n0 = (bid % tilesX) * BN;
  f32x4 acc[MT][NT] = {};
  for (int k0 = 0; k0 < K; k0 += BK) {
    __syncthreads();
#pragma unroll
    for (int i = 0; i < IA; ++i) {
      int c = i * 256 + tid, row = c >> 3, c8 = (c & 7) * 8;
      load16_to_lds(&A[(size_t)(m0 + row) * K + k0 + c8], lA + c * 8);
    }
#pragma unroll
    for (int i = 0; i < IB; ++i) {
      int c = i * 256 + tid, row = c >> 3, c8 = (c & 7) * 8;
      load16_to_lds(&BT[(size_t)(n0 + row) * K + k0 + c8], lB + c * 8);
    }
    __syncthreads();
#pragma unroll
    for (int kt = 0; kt < 2; ++kt) {
      s16x8 a[MT], b[NT];
#pragma unroll
      for (int mi = 0; mi < MT; ++mi)
        a[mi] = *(const s16x8*)&lA[(wr * BM2 + mi * 16 + fm) * BK + kt * 32 + q8];
#pragma unroll
      for (int ni = 0; ni < NT; ++ni)
        b[ni] = *(const s16x8*)&lB[(wc * BN2 + ni * 16 + fm) * BK + kt * 32 + q8];
#pragma unroll
      for (int mi = 0; mi < MT; ++mi)
#pragma unroll
        for (int ni = 0; ni < NT; ++ni)
          acc[mi][ni] = __builtin_amdgcn_mfma_f32_16x16x32_bf16(a[mi], b[ni], acc[mi][ni], 0, 0, 0);
    }
  }
#pragma unroll
  for (int mi = 0; mi < MT; ++mi)
#pragma unroll
    for (int ni = 0; ni < NT; ++ni)
#pragma unroll
      for (int r = 0; r < 4; ++r) {
        int row = m0 + wr * BM2 + mi * 16 + q4 * 4 + r;
        int col = n0 + wc * BN2 + ni * 16 + fm;
        if constexpr (OUT16)
          ((unsigned short*)Cp)[(size_t)row * N + col] = f2bf(acc[mi][ni][r]);
        else
          ((float*)Cp)[(size_t)row * N + col] = acc[mi][ni][r];
      }
}

__global__ __launch_bounds__(256) void gemm1_kernel(const unsigned short* __restrict__ A,
                                                    const unsigned short* __restrict__ BT,
                                                    unsigned short* __restrict__ Cc) {
  __shared__ __align__(16) unsigned short smem[(128 + 96) * 64];
  gemm_body<128, 96, true>(A, BT, Cc, QKV_LD, C_DIM, 16, smem, smem + 128 * 64,
                           threadIdx.x, blockIdx.x);
}
__global__ __launch_bounds__(256) void gemm2_kernel(const unsigned short* __restrict__ A,
                                                    const unsigned short* __restrict__ BT,
                                                    float* __restrict__ Cc) {
  __shared__ __align__(16) unsigned short smem[(64 + 64) * 64];
  gemm_body<64, 64, false>(A, BT, Cc, C_DIM, C_DIM, 8, smem, smem + 64 * 64,
                           threadIdx.x, blockIdx.x);
}

// ---------------------------------------------------------------------------
// MFMA attention: 512 blocks (8 heads x 64 t-tiles of 32 slots). (unchanged)
//   S[32][128] = Q·K^T (MFMA) -> LDS fp32 -> shuffle softmax -> P bf16 in LDS
//   -> V^T staged over K's buffer -> O[32][64] = P·V^T (MFMA) -> scatter to Y.
// ---------------------------------------------------------------------------
__global__ __launch_bounds__(256) void attn_kernel(const unsigned short* __restrict__ qkvbf,
                                                   const int* __restrict__ perms,
                                                   unsigned short* __restrict__ Ybf) {
  __shared__ __align__(16) unsigned char smem[48768];
  int* ow            = (int*)smem;                           // [128]
  unsigned short* lQ = (unsigned short*)(smem + 512);        // [32][72]
  unsigned short* lK = (unsigned short*)(smem + 5120);       // [128][72]
  float* Sb          = (float*)(smem + 23552);               // [32][129]
  unsigned short* lP = (unsigned short*)(smem + 40064);      // [32][136]
  unsigned short* lVT= (unsigned short*)(smem + 5120);       // [64][136] overlays lK

  const int tid = threadIdx.x, bid = blockIdx.x;
  const int lane = tid & 63, w = tid >> 6;
  const int fm = lane & 15, q8 = (lane >> 4) * 8, q4 = lane >> 4;
  const int h = bid >> 6;
  const int t0 = (bid & 63) << 5;

  if (tid < 128) {
    int pi = t0 - 48 + tid;
    int idx = min(max(pi, 0), T_DIM - 1);
    ow[tid] = perms[h * T_DIM + idx];
  }
  __syncthreads();

#pragma unroll
  for (int it = 0; it < 4; ++it) {
    int c = it * 256 + tid;
    int row = c >> 3, k8 = c & 7;
    uint4 d = *(const uint4*)(qkvbf + (size_t)ow[row] * QKV_LD + C_DIM + h * 64 + k8 * 8);
    *(uint4*)(lK + row * 72 + k8 * 8) = d;
  }
  {
    int row = tid >> 3, k8 = tid & 7;
    uint4 d = *(const uint4*)(qkvbf + (size_t)ow[48 + row] * QKV_LD + h * 64 + k8 * 8);
    *(uint4*)(lQ + row * 72 + k8 * 8) = d;
  }
  __syncthreads();

  // S = Q·K^T via MFMA; wave w owns key-cols [w*32, w*32+32)
  {
    f32x4 accs[2][2] = {};
#pragma unroll
    for (int kt = 0; kt < 2; ++kt) {
      s16x8 aq[2];
#pragma unroll
      for (int mi = 0; mi < 2; ++mi)
        aq[mi] = *(const s16x8*)&lQ[(mi * 16 + fm) * 72 + kt * 32 + q8];
#pragma unroll
      for (int ni = 0; ni < 2; ++ni) {
        s16x8 bk = *(const s16x8*)&lK[(w * 32 + ni * 16 + fm) * 72 + kt * 32 + q8];
#pragma unroll
        for (int mi = 0; mi < 2; ++mi)
          accs[mi][ni] = __builtin_amdgcn_mfma_f32_16x16x32_bf16(aq[mi], bk, accs[mi][ni], 0, 0, 0);
      }
    }
#pragma unroll
    for (int mi = 0; mi < 2; ++mi)
#pragma unroll
      for (int ni = 0; ni < 2; ++ni)
#pragma unroll
        for (int r = 0; r < 4; ++r)
          Sb[(mi * 16 + q4 * 4 + r) * 129 + w * 32 + ni * 16 + fm] = accs[mi][ni][r] * 0.125f;
  }
  __syncthreads();

  // stage V^T [64 d][128 key] over lK (K frag reads finished above)
#pragma unroll
  for (int it = 0; it < 4; ++it) {
    int c = it * 256 + tid;
    int j = c >> 3, d0 = (c & 7) * 8;
    uint4 v = *(const uint4*)(qkvbf + (size_t)ow[j] * QKV_LD + 2 * C_DIM + h * 64 + d0);
    lVT[(d0 + 0) * 136 + j] = (unsigned short)(v.x & 0xffff);
    lVT[(d0 + 1) * 136 + j] = (unsigned short)(v.x >> 16);
    lVT[(d0 + 2) * 136 + j] = (unsigned short)(v.y & 0xffff);
    lVT[(d0 + 3) * 136 + j] = (unsigned short)(v.y >> 16);
    lVT[(d0 + 4) * 136 + j] = (unsigned short)(v.z & 0xffff);
    lVT[(d0 + 5) * 136 + j] = (unsigned short)(v.z >> 16);
    lVT[(d0 + 6) * 136 + j] = (unsigned short)(v.w & 0xffff);
    lVT[(d0 + 7) * 136 + j] = (unsigned short)(v.w >> 16);
  }

  // softmax: wave w owns q-rows w*8..w*8+7; lane owns cols (lane, lane+64)
  for (int si = 0; si < 8; ++si) {
    const int s = w * 8 + si;
    const int p = ow[48 + s];
    const int c1 = lane + 64;
    const float v0 = Sb[s * 129 + lane];
    const float v1 = Sb[s * 129 + c1];
    const int pi0 = t0 - 48 + lane;
    const bool valid0 = (lane >= s) && (pi0 >= 0) && (pi0 < T_DIM) && (ow[lane] <= p);
    const bool valid1 = (lane <= s + 32) && (pi0 + 64 < T_DIM) && (ow[c1] <= p);
    float mx = fmaxf(valid0 ? v0 : -FLT_MAX, valid1 ? v1 : -FLT_MAX);
#pragma unroll
    for (int off = 32; off > 0; off >>= 1) mx = fmaxf(mx, __shfl_xor(mx, off, 64));
    const float e0 = valid0 ? __expf(v0 - mx) : 0.f;
    const float e1 = valid1 ? __expf(v1 - mx) : 0.f;
    float sum = e0 + e1;
#pragma unroll
    for (int off = 32; off > 0; off >>= 1) sum += __shfl_xor(sum, off, 64);
    const float inv = 1.f / sum;
    lP[s * 136 + lane] = valid0 ? f2bf(e0 * inv) : (unsigned short)0;
    lP[s * 136 + c1]   = valid1 ? f2bf(e1 * inv) : (unsigned short)0;
  }
  __syncthreads();

  // O = P·V^T via MFMA; wave (wr,wc): m-tile wr, n-tiles wc*2+{0,1}
  {
    const int wr = w >> 1, wc = w & 1;
    f32x4 acco[2] = {};
#pragma unroll
    for (int kt = 0; kt < 4; ++kt) {
      s16x8 ap = *(const s16x8*)&lP[(wr * 16 + fm) * 136 + kt * 32 + q8];
#pragma unroll
      for (int ni = 0; ni < 2; ++ni) {
        s16x8 bv = *(const s16x8*)&lVT[((wc * 2 + ni) * 16 + fm) * 136 + kt * 32 + q8];
        acco[ni] = __builtin_amdgcn_mfma_f32_16x16x32_bf16(ap, bv, acco[ni], 0, 0, 0);
      }
    }
#pragma unroll
    for (int ni = 0; ni < 2; ++ni)
#pragma unroll
      for (int r = 0; r < 4; ++r) {
        int q = wr * 16 + q4 * 4 + r;
        int d = (wc * 2 + ni) * 16 + fm;
        Ybf[(size_t)ow[48 + q] * C_DIM + h * 64 + d] = f2bf(acco[ni][r]);
      }
  }
}

// ---------------------------------------------------------------------------
extern "C" void kernel_launch(void* const* d_in, const int* in_sizes, int n_in,
                              void* d_out, int out_size, void* d_ws, size_t ws_size,
                              hipStream_t stream) {
  const float* x     = (const float*)d_in[0];
  const float* Wqkv  = (const float*)d_in[1];
  const float* Wout  = (const float*)d_in[2];
  const int*   perms = (const int*)d_in[3];
  float* out = (float*)d_out;
  unsigned short* ws = (unsigned short*)d_ws;

  unsigned short* xbf   = ws;                    // 2048*512
  unsigned short* WqkvT = xbf + 1048576;         // [1536][512]
  unsigned short* WoutT = WqkvT + 786432;        // [512][512]
  unsigned short* qkvbf = WoutT + 262144;        // [2048][1536]
  unsigned short* Ybf   = qkvbf + 3145728;       // [2048][512]

  prep_kernel<<<NBLK, 256, 0, stream>>>(x, Wqkv, Wout, xbf, WqkvT, WoutT);
  gemm1_kernel<<<256, 256, 0, stream>>>(xbf, WqkvT, qkvbf);
  attn_kernel<<<NBLK, 256, 0, stream>>>(qkvbf, perms, Ybf);
  gemm2_kernel<<<256, 256, 0, stream>>>(Ybf, WoutT, out);
}

// Round 10
// 94.866 us; speedup vs baseline: 1.0261x; 1.0261x over previous
//
#include <hip/hip_runtime.h>
#include <float.h>
#include <math.h>

#define T_DIM 2048
#define C_DIM 512
#define QKV_LD 1536
#define NBLK 512

typedef float f32x4 __attribute__((ext_vector_type(4)));
typedef short s16x8 __attribute__((ext_vector_type(8)));

__device__ __forceinline__ unsigned short f2bf(float f) {
  unsigned u = __float_as_uint(f);
  return (unsigned short)((u + 0x7fffu + ((u >> 16) & 1u)) >> 16);
}

// async 16B global->LDS; LDS dest must be wave-uniform base + lane*16.
__device__ __forceinline__ void load16_to_lds(const void* g, void* l) {
  __builtin_amdgcn_global_load_lds(
      (const __attribute__((address_space(1))) unsigned int*)g,
      (__attribute__((address_space(3))) unsigned int*)(unsigned int)(unsigned long long)l,
      16, 0, 0);
}

// ---------------------------------------------------------------------------
// prep: cast x -> bf16; transpose+cast Wqkv, Wout.  512 blocks. (R6 config)
// ---------------------------------------------------------------------------
__global__ __launch_bounds__(256) void prep_kernel(const float* __restrict__ x,
                                                   const float* __restrict__ Wqkv,
                                                   const float* __restrict__ Wout,
                                                   unsigned short* __restrict__ xbf,
                                                   unsigned short* __restrict__ WqkvT,
                                                   unsigned short* __restrict__ WoutT) {
  __shared__ float tile[32][33];
  const int tid = threadIdx.x, bid = blockIdx.x;

  const float4* xs4 = (const float4*)x;
  for (int i = bid * 256 + tid; i < (T_DIM * C_DIM) / 4; i += NBLK * 256) {
    float4 v = xs4[i];
    ushort4 o;
    o.x = f2bf(v.x); o.y = f2bf(v.y); o.z = f2bf(v.z); o.w = f2bf(v.w);
    ((ushort4*)xbf)[i] = o;
  }
  const int tx = tid & 31, ty = tid >> 5;
  for (int tt = bid; tt < 1024; tt += NBLK) {
    const float* src; unsigned short* dst; int Cc, R, bx, by;
    if (tt < 768) { src = Wqkv; dst = WqkvT; Cc = QKV_LD; R = C_DIM; bx = (tt % 48) * 32; by = (tt / 48) * 32; }
    else { int u = tt - 768; src = Wout; dst = WoutT; Cc = C_DIM; R = C_DIM; bx = (u & 15) * 32; by = (u >> 4) * 32; }
    __syncthreads();
#pragma unroll
    for (int i = 0; i < 4; ++i) { int r = ty + i * 8; tile[r][tx] = src[(size_t)(by + r) * Cc + bx + tx]; }
    __syncthreads();
#pragma unroll
    for (int i = 0; i < 4; ++i) { int r = ty + i * 8; dst[(size_t)(bx + r) * R + by + tx] = f2bf(tile[tx][r]); }
  }
}

// ---------------------------------------------------------------------------
// bf16 MFMA GEMM: C = A[M,K] * BT[N,K]^T.  One tile per block, BK=32 (R6 —
// best measured; BK=64/BN=96 variants were noise-neutral or worse).
// ---------------------------------------------------------------------------
template <int BM, int BN, bool OUT16>
__device__ __forceinline__ void gemm_body(const unsigned short* __restrict__ A,
                                          const unsigned short* __restrict__ BT,
                                          void* __restrict__ Cp,
                                          int N, int K, int tilesX,
                                          unsigned short* lA, unsigned short* lB,
                                          int tid, int bid) {
  constexpr int BK = 32;
  constexpr int BM2 = BM / 2, BN2 = BN / 2;
  constexpr int MT = BM2 / 16, NT = BN2 / 16;
  constexpr int IA = BM / 64;
  constexpr int IB = BN / 64;
  const int lane = tid & 63, w = tid >> 6, wr = w >> 1, wc = w & 1;
  const int fm = lane & 15, q8 = (lane >> 4) * 8, q4 = lane >> 4;

  const int m0 = (bid / tilesX) * BM, n0 = (bid % tilesX) * BN;
  f32x4 acc[MT][NT] = {};
  for (int k0 = 0; k0 < K; k0 += BK) {
    __syncthreads();
#pragma unroll
    for (int i = 0; i < IA; ++i) {
      int c = i * 256 + tid, row = c >> 2, c8 = (c & 3) * 8;
      load16_to_lds(&A[(size_t)(m0 + row) * K + k0 + c8], lA + c * 8);
    }
#pragma unroll
    for (int i = 0; i < IB; ++i) {
      int c = i * 256 + tid, row = c >> 2, c8 = (c & 3) * 8;
      load16_to_lds(&BT[(size_t)(n0 + row) * K + k0 + c8], lB + c * 8);
    }
    __syncthreads();
    s16x8 a[MT], b[NT];
#pragma unroll
    for (int mi = 0; mi < MT; ++mi)
      a[mi] = *(const s16x8*)&lA[(wr * BM2 + mi * 16 + fm) * BK + q8];
#pragma unroll
    for (int ni = 0; ni < NT; ++ni)
      b[ni] = *(const s16x8*)&lB[(wc * BN2 + ni * 16 + fm) * BK + q8];
#pragma unroll
    for (int mi = 0; mi < MT; ++mi)
#pragma unroll
      for (int ni = 0; ni < NT; ++ni)
        acc[mi][ni] = __builtin_amdgcn_mfma_f32_16x16x32_bf16(a[mi], b[ni], acc[mi][ni], 0, 0, 0);
  }
#pragma unroll
  for (int mi = 0; mi < MT; ++mi)
#pragma unroll
    for (int ni = 0; ni < NT; ++ni)
#pragma unroll
      for (int r = 0; r < 4; ++r) {
        int row = m0 + wr * BM2 + mi * 16 + q4 * 4 + r;
        int col = n0 + wc * BN2 + ni * 16 + fm;
        if constexpr (OUT16)
          ((unsigned short*)Cp)[(size_t)row * N + col] = f2bf(acc[mi][ni][r]);
        else
          ((float*)Cp)[(size_t)row * N + col] = acc[mi][ni][r];
      }
}

__global__ __launch_bounds__(256) void gemm1_kernel(const unsigned short* __restrict__ A,
                                                    const unsigned short* __restrict__ BT,
                                                    unsigned short* __restrict__ Cc) {
  __shared__ __align__(16) unsigned short smem[(128 + 64) * 32];
  gemm_body<128, 64, true>(A, BT, Cc, QKV_LD, C_DIM, 24, smem, smem + 128 * 32,
                           threadIdx.x, blockIdx.x);
}
__global__ __launch_bounds__(256) void gemm2_kernel(const unsigned short* __restrict__ A,
                                                    const unsigned short* __restrict__ BT,
                                                    float* __restrict__ Cc) {
  __shared__ __align__(16) unsigned short smem[(64 + 64) * 32];
  gemm_body<64, 64, false>(A, BT, Cc, C_DIM, C_DIM, 8, smem, smem + 64 * 32,
                           threadIdx.x, blockIdx.x);
}

// ---------------------------------------------------------------------------
// MFMA attention: 512 blocks (8 heads x 64 t-tiles of 32 slots).
// Change vs R6: V^T staging remapped (lanes span rows, not dims) ->
// conflict-free LDS banks, and row-pairs packed into ds_write_b32
// (16 writes/thread instead of 32). V bits identical -> bitwise-same output.
// ---------------------------------------------------------------------------
__global__ __launch_bounds__(256) void attn_kernel(const unsigned short* __restrict__ qkvbf,
                                                   const int* __restrict__ perms,
                                                   unsigned short* __restrict__ Ybf) {
  __shared__ __align__(16) unsigned char smem[48768];
  int* ow            = (int*)smem;                           // [128]
  unsigned short* lQ = (unsigned short*)(smem + 512);        // [32][72]
  unsigned short* lK = (unsigned short*)(smem + 5120);       // [128][72]
  float* Sb          = (float*)(smem + 23552);               // [32][129]
  unsigned short* lP = (unsigned short*)(smem + 40064);      // [32][136]
  unsigned short* lVT= (unsigned short*)(smem + 5120);       // [64][136] overlays lK

  const int tid = threadIdx.x, bid = blockIdx.x;
  const int lane = tid & 63, w = tid >> 6;
  const int fm = lane & 15, q8 = (lane >> 4) * 8, q4 = lane >> 4;
  const int h = bid >> 6;
  const int t0 = (bid & 63) << 5;

  if (tid < 128) {
    int pi = t0 - 48 + tid;
    int idx = min(max(pi, 0), T_DIM - 1);
    ow[tid] = perms[h * T_DIM + idx];
  }
  __syncthreads();

#pragma unroll
  for (int it = 0; it < 4; ++it) {
    int c = it * 256 + tid;
    int row = c >> 3, k8 = c & 7;
    uint4 d = *(const uint4*)(qkvbf + (size_t)ow[row] * QKV_LD + C_DIM + h * 64 + k8 * 8);
    *(uint4*)(lK + row * 72 + k8 * 8) = d;
  }
  {
    int row = tid >> 3, k8 = tid & 7;
    uint4 d = *(const uint4*)(qkvbf + (size_t)ow[48 + row] * QKV_LD + h * 64 + k8 * 8);
    *(uint4*)(lQ + row * 72 + k8 * 8) = d;
  }
  __syncthreads();

  // S = Q·K^T via MFMA; wave w owns key-cols [w*32, w*32+32)
  {
    f32x4 accs[2][2] = {};
#pragma unroll
    for (int kt = 0; kt < 2; ++kt) {
      s16x8 aq[2];
#pragma unroll
      for (int mi = 0; mi < 2; ++mi)
        aq[mi] = *(const s16x8*)&lQ[(mi * 16 + fm) * 72 + kt * 32 + q8];
#pragma unroll
      for (int ni = 0; ni < 2; ++ni) {
        s16x8 bk = *(const s16x8*)&lK[(w * 32 + ni * 16 + fm) * 72 + kt * 32 + q8];
#pragma unroll
        for (int mi = 0; mi < 2; ++mi)
          accs[mi][ni] = __builtin_amdgcn_mfma_f32_16x16x32_bf16(aq[mi], bk, accs[mi][ni], 0, 0, 0);
      }
    }
#pragma unroll
    for (int mi = 0; mi < 2; ++mi)
#pragma unroll
      for (int ni = 0; ni < 2; ++ni)
#pragma unroll
        for (int r = 0; r < 4; ++r)
          Sb[(mi * 16 + q4 * 4 + r) * 129 + w * 32 + ni * 16 + fm] = accs[mi][ni][r] * 0.125f;
  }
  __syncthreads();

  // stage V^T [64 d][128 key] over lK.  Work item c2: row-pair r = c2&63,
  // dim-chunk d0 = (c2>>6)*8.  Consecutive lanes -> consecutive r ->
  // addr/4 = (d0+i)*68 + r -> conflict-free banks.  b32 packs rows 2r,2r+1.
#pragma unroll
  for (int it = 0; it < 2; ++it) {
    int c2 = it * 256 + tid;
    int r = c2 & 63, d0 = (c2 >> 6) * 8;
    uint4 va = *(const uint4*)(qkvbf + (size_t)ow[2 * r]     * QKV_LD + 2 * C_DIM + h * 64 + d0);
    uint4 vb = *(const uint4*)(qkvbf + (size_t)ow[2 * r + 1] * QKV_LD + 2 * C_DIM + h * 64 + d0);
    unsigned* dst0 = (unsigned*)(lVT + (d0 + 0) * 136 + 2 * r);
    // word for dim d: lo16 = V[2r][d], hi16 = V[2r+1][d]
    *(unsigned*)(lVT + (d0 + 0) * 136 + 2 * r) = (va.x & 0xffffu) | (vb.x << 16);
    *(unsigned*)(lVT + (d0 + 1) * 136 + 2 * r) = (va.x >> 16) | (vb.x & 0xffff0000u);
    *(unsigned*)(lVT + (d0 + 2) * 136 + 2 * r) = (va.y & 0xffffu) | (vb.y << 16);
    *(unsigned*)(lVT + (d0 + 3) * 136 + 2 * r) = (va.y >> 16) | (vb.y & 0xffff0000u);
    *(unsigned*)(lVT + (d0 + 4) * 136 + 2 * r) = (va.z & 0xffffu) | (vb.z << 16);
    *(unsigned*)(lVT + (d0 + 5) * 136 + 2 * r) = (va.z >> 16) | (vb.z & 0xffff0000u);
    *(unsigned*)(lVT + (d0 + 6) * 136 + 2 * r) = (va.w & 0xffffu) | (vb.w << 16);
    *(unsigned*)(lVT + (d0 + 7) * 136 + 2 * r) = (va.w >> 16) | (vb.w & 0xffff0000u);
    (void)dst0;
  }

  // softmax: wave w owns q-rows w*8..w*8+7; lane owns cols (lane, lane+64)
  for (int si = 0; si < 8; ++si) {
    const int s = w * 8 + si;
    const int p = ow[48 + s];
    const int c1 = lane + 64;
    const float v0 = Sb[s * 129 + lane];
    const float v1 = Sb[s * 129 + c1];
    const int pi0 = t0 - 48 + lane;
    const bool valid0 = (lane >= s) && (pi0 >= 0) && (pi0 < T_DIM) && (ow[lane] <= p);
    const bool valid1 = (lane <= s + 32) && (pi0 + 64 < T_DIM) && (ow[c1] <= p);
    float mx = fmaxf(valid0 ? v0 : -FLT_MAX, valid1 ? v1 : -FLT_MAX);
#pragma unroll
    for (int off = 32; off > 0; off >>= 1) mx = fmaxf(mx, __shfl_xor(mx, off, 64));
    const float e0 = valid0 ? __expf(v0 - mx) : 0.f;
    const float e1 = valid1 ? __expf(v1 - mx) : 0.f;
    float sum = e0 + e1;
#pragma unroll
    for (int off = 32; off > 0; off >>= 1) sum += __shfl_xor(sum, off, 64);
    const float inv = 1.f / sum;
    lP[s * 136 + lane] = valid0 ? f2bf(e0 * inv) : (unsigned short)0;
    lP[s * 136 + c1]   = valid1 ? f2bf(e1 * inv) : (unsigned short)0;
  }
  __syncthreads();

  // O = P·V^T via MFMA; wave (wr,wc): m-tile wr, n-tiles wc*2+{0,1}
  {
    const int wr = w >> 1, wc = w & 1;
    f32x4 acco[2] = {};
#pragma unroll
    for (int kt = 0; kt < 4; ++kt) {
      s16x8 ap = *(const s16x8*)&lP[(wr * 16 + fm) * 136 + kt * 32 + q8];
#pragma unroll
      for (int ni = 0; ni < 2; ++ni) {
        s16x8 bv = *(const s16x8*)&lVT[((wc * 2 + ni) * 16 + fm) * 136 + kt * 32 + q8];
        acco[ni] = __builtin_amdgcn_mfma_f32_16x16x32_bf16(ap, bv, acco[ni], 0, 0, 0);
      }
    }
#pragma unroll
    for (int ni = 0; ni < 2; ++ni)
#pragma unroll
      for (int r = 0; r < 4; ++r) {
        int q = wr * 16 + q4 * 4 + r;
        int d = (wc * 2 + ni) * 16 + fm;
        Ybf[(size_t)ow[48 + q] * C_DIM + h * 64 + d] = f2bf(acco[ni][r]);
      }
  }
}

// ---------------------------------------------------------------------------
extern "C" void kernel_launch(void* const* d_in, const int* in_sizes, int n_in,
                              void* d_out, int out_size, void* d_ws, size_t ws_size,
                              hipStream_t stream) {
  const float* x     = (const float*)d_in[0];
  const float* Wqkv  = (const float*)d_in[1];
  const float* Wout  = (const float*)d_in[2];
  const int*   perms = (const int*)d_in[3];
  float* out = (float*)d_out;
  unsigned short* ws = (unsigned short*)d_ws;

  unsigned short* xbf   = ws;                    // 2048*512
  unsigned short* WqkvT = xbf + 1048576;         // [1536][512]
  unsigned short* WoutT = WqkvT + 786432;        // [512][512]
  unsigned short* qkvbf = WoutT + 262144;        // [2048][1536]
  unsigned short* Ybf   = qkvbf + 3145728;       // [2048][512]

  prep_kernel<<<NBLK, 256, 0, stream>>>(x, Wqkv, Wout, xbf, WqkvT, WoutT);
  gemm1_kernel<<<384, 256, 0, stream>>>(xbf, WqkvT, qkvbf);
  attn_kernel<<<NBLK, 256, 0, stream>>>(qkvbf, perms, Ybf);
  gemm2_kernel<<<256, 256, 0, stream>>>(Ybf, WoutT, out);
}